// Round 1
// baseline (182.227 us; speedup 1.0000x reference)
//
#include <hip/hip_runtime.h>

#define BB 4
#define CC 3
#define HH 384
#define WW 384
#define KK 15
#define PP 7
#define HP (HH + 2*PP)   // 398
#define WP 400           // padded row stride (400*4B = 1600B, 16B aligned rows)
#define HW (HH*WW)       // 147456

// ---- pad kernel: build zero-padded data in workspace -----------------------
__global__ __launch_bounds__(256) void pad_kernel(const float* __restrict__ data,
                                                  float* __restrict__ pad) {
    int idx = blockIdx.x * 256 + threadIdx.x;
    const int total = BB * CC * HP * WP;
    if (idx >= total) return;
    int x  = idx % WP;
    int y  = (idx / WP) % HP;
    int bc = idx / (WP * HP);
    int dy = y - PP, dx = x - PP;
    float v = 0.f;
    if (dy >= 0 && dy < HH && dx >= 0 && dx < WW)
        v = data[(size_t)bc * HW + dy * WW + dx];
    pad[idx] = v;
}

// ---- main kernel: no bounds checks, 4 px/thread ----------------------------
__global__ __launch_bounds__(256) void conv_kernel(const float* __restrict__ kern,
                                                   const float* __restrict__ pad,
                                                   float* __restrict__ out) {
    const int t     = blockIdx.x * 256 + threadIdx.x;   // 0 .. B*HW/4 - 1
    const int per_b = HW / 4;                           // 36864
    const int b   = t / per_b;
    const int r   = t - b * per_b;
    const int pix = r * 4;
    const int y   = pix / WW;
    const int x   = pix - y * WW;

    const float* kb = kern + (size_t)b * (KK * KK) * HW + pix;

    float acc[CC][4];
    #pragma unroll
    for (int c = 0; c < CC; ++c)
        #pragma unroll
        for (int k = 0; k < 4; ++k) acc[c][k] = 0.f;

    #pragma unroll 1
    for (int u = 0; u < KK; ++u) {
        // 15 kernel taps for this u-row, one float4 (4 pixels) each
        float4 kv[KK];
        #pragma unroll
        for (int v = 0; v < KK; ++v)
            kv[v] = *(const float4*)(kb + (size_t)(u * KK + v) * HW);

        const int prow = y + 2 * PP - u;   // padded row index: y + 14 - u

        #pragma unroll
        for (int c = 0; c < CC; ++c) {
            const float* pr = pad + ((size_t)(b * CC + c) * HP + prow) * WP + x;
            float win[20];
            #pragma unroll
            for (int w = 0; w < 5; ++w) {
                float4 d = *(const float4*)(pr + w * 4);
                win[w * 4 + 0] = d.x;
                win[w * 4 + 1] = d.y;
                win[w * 4 + 2] = d.z;
                win[w * 4 + 3] = d.w;
            }
            #pragma unroll
            for (int v = 0; v < KK; ++v) {
                const int s = (KK - 1) - v;        // data shift 14-v
                const float* kvp = (const float*)&kv[v];
                #pragma unroll
                for (int k = 0; k < 4; ++k)
                    acc[c][k] = fmaf(kvp[k], win[s + k], acc[c][k]);
            }
        }
    }

    #pragma unroll
    for (int c = 0; c < CC; ++c) {
        float4 o = make_float4(acc[c][0], acc[c][1], acc[c][2], acc[c][3]);
        *(float4*)(out + (size_t)(b * CC + c) * HW + pix) = o;
    }
}

// ---- fallback: bounds-checked, reads data directly (if ws too small) -------
__global__ __launch_bounds__(256) void conv_kernel_safe(const float* __restrict__ kern,
                                                        const float* __restrict__ data,
                                                        float* __restrict__ out) {
    const int t     = blockIdx.x * 256 + threadIdx.x;
    const int per_b = HW / 4;
    const int b   = t / per_b;
    const int r   = t - b * per_b;
    const int pix = r * 4;
    const int y   = pix / WW;
    const int x   = pix - y * WW;

    const float* kb = kern + (size_t)b * (KK * KK) * HW + pix;

    float acc[CC][4];
    #pragma unroll
    for (int c = 0; c < CC; ++c)
        #pragma unroll
        for (int k = 0; k < 4; ++k) acc[c][k] = 0.f;

    #pragma unroll 1
    for (int u = 0; u < KK; ++u) {
        float4 kv[KK];
        #pragma unroll
        for (int v = 0; v < KK; ++v)
            kv[v] = *(const float4*)(kb + (size_t)(u * KK + v) * HW);

        const int drow  = y + PP - u;            // data row y + 7 - u
        const bool rowok = (drow >= 0) && (drow < HH);

        #pragma unroll
        for (int c = 0; c < CC; ++c) {
            const float* dr = data + (size_t)(b * CC + c) * HW + drow * WW;
            float win[20];
            #pragma unroll
            for (int i = 0; i < 20; ++i) {
                int col = x + i - PP;
                win[i] = (rowok && col >= 0 && col < WW) ? dr[col] : 0.f;
            }
            #pragma unroll
            for (int v = 0; v < KK; ++v) {
                const int s = (KK - 1) - v;
                const float* kvp = (const float*)&kv[v];
                #pragma unroll
                for (int k = 0; k < 4; ++k)
                    acc[c][k] = fmaf(kvp[k], win[s + k], acc[c][k]);
            }
        }
    }

    #pragma unroll
    for (int c = 0; c < CC; ++c) {
        float4 o = make_float4(acc[c][0], acc[c][1], acc[c][2], acc[c][3]);
        *(float4*)(out + (size_t)(b * CC + c) * HW + pix) = o;
    }
}

extern "C" void kernel_launch(void* const* d_in, const int* in_sizes, int n_in,
                              void* d_out, int out_size, void* d_ws, size_t ws_size,
                              hipStream_t stream) {
    const float* data = (const float*)d_in[0];   // [B, C, H, W]
    const float* kern = (const float*)d_in[1];   // [B, K, K, H, W]
    float* out = (float*)d_out;                  // [B, C, H, W]

    const size_t padBytes = (size_t)BB * CC * HP * WP * sizeof(float);
    const int nThreads = BB * HW / 4;            // 147456
    const int nBlocks  = nThreads / 256;         // 576

    if (ws_size >= padBytes) {
        float* pad = (float*)d_ws;
        const int totalPad = BB * CC * HP * WP;
        pad_kernel<<<(totalPad + 255) / 256, 256, 0, stream>>>(data, pad);
        conv_kernel<<<nBlocks, 256, 0, stream>>>(kern, pad, out);
    } else {
        conv_kernel_safe<<<nBlocks, 256, 0, stream>>>(kern, data, out);
    }
}

// Round 2
// 111.978 us; speedup vs baseline: 1.6273x; 1.6273x over previous
//
#include <hip/hip_runtime.h>

#define BB 4
#define CC 3
#define HH 384
#define WW 384
#define KK 15
#define PP 7
#define HP (HH + 2*PP)   // 398
#define WP 400           // padded row stride (400*4B, 16B-aligned rows)
#define HW (HH*WW)       // 147456

#define TX 128           // tile width (pixels)
#define TY 8             // tile height (pixels)
#define SROWS (TY + 2*PP)       // 22 staged rows
#define SCOLS (TX + 16)         // 144 staged cols (128 + up to 20-col window, padded)
#define NTX (WW / TX)    // 3
#define NTY (HH / TY)    // 48

// ---- pad kernel: build zero-padded data in workspace -----------------------
__global__ __launch_bounds__(256) void pad_kernel(const float* __restrict__ data,
                                                  float* __restrict__ pad) {
    int idx = blockIdx.x * 256 + threadIdx.x;
    const int total = BB * CC * HP * WP;
    if (idx >= total) return;
    int x  = idx % WP;
    int y  = (idx / WP) % HP;
    int bc = idx / (WP * HP);
    int dy = y - PP, dx = x - PP;
    float v = 0.f;
    if (dy >= 0 && dy < HH && dx >= 0 && dx < WW)
        v = data[(size_t)bc * HW + dy * WW + dx];
    pad[idx] = v;
}

// ---- main kernel: 128x8 tile staged in LDS, 4 px/thread --------------------
__global__ __launch_bounds__(256) void conv_tiled(const float* __restrict__ kern,
                                                  const float* __restrict__ pad,
                                                  float* __restrict__ out) {
    const int tid = threadIdx.x;
    const int blk = blockIdx.x;                 // 0 .. BB*NTY*NTX-1
    const int b   = blk / (NTY * NTX);
    const int r2  = blk - b * (NTY * NTX);
    const int ty  = r2 / NTX;
    const int tx  = r2 - ty * NTX;
    const int x0  = tx * TX;
    const int y0  = ty * TY;

    __shared__ __align__(16) float smem[CC][SROWS][SCOLS];   // 38016 B

    // ---- stage pad window into LDS (vectorized, coalesced) ----
    // 3 ch x 22 rows x 36 float4 = 2376 float4 loads
    const int NV = CC * SROWS * (SCOLS / 4);
    for (int i = tid; i < NV; i += 256) {
        int cx = i % (SCOLS / 4);
        int r  = (i / (SCOLS / 4)) % SROWS;
        int c  = i / ((SCOLS / 4) * SROWS);
        float4 d = *(const float4*)(pad + ((size_t)(b * CC + c) * HP + y0 + r) * WP
                                        + x0 + cx * 4);
        *(float4*)&smem[c][r][cx * 4] = d;
    }
    __syncthreads();

    const int lx = tid & 31;       // x quad within tile
    const int ly = tid >> 5;       // row within tile
    const int x  = x0 + lx * 4;
    const int y  = y0 + ly;
    const int pix = y * WW + x;

    const float* kb = kern + (size_t)b * (KK * KK) * HW + pix;

    float acc[CC][4];
    #pragma unroll
    for (int c = 0; c < CC; ++c)
        #pragma unroll
        for (int k = 0; k < 4; ++k) acc[c][k] = 0.f;

    #pragma unroll 1
    for (int u = 0; u < KK; ++u) {
        // 15 kernel taps for this u-row, one float4 (4 pixels) each — only HBM stream
        float4 kv[KK];
        #pragma unroll
        for (int v = 0; v < KK; ++v)
            kv[v] = *(const float4*)(kb + (size_t)(u * KK + v) * HW);

        const int rr = ly + 2 * PP - u;    // staged row: ly + 14 - u, in [0,21]

        #pragma unroll
        for (int c = 0; c < CC; ++c) {
            float win[20];
            #pragma unroll
            for (int w = 0; w < 5; ++w) {
                float4 d = *(const float4*)&smem[c][rr][lx * 4 + w * 4];
                win[w * 4 + 0] = d.x;
                win[w * 4 + 1] = d.y;
                win[w * 4 + 2] = d.z;
                win[w * 4 + 3] = d.w;
            }
            #pragma unroll
            for (int v = 0; v < KK; ++v) {
                const int s = (KK - 1) - v;        // data shift 14-v
                const float* kvp = (const float*)&kv[v];
                #pragma unroll
                for (int k = 0; k < 4; ++k)
                    acc[c][k] = fmaf(kvp[k], win[s + k], acc[c][k]);
            }
        }
    }

    #pragma unroll
    for (int c = 0; c < CC; ++c) {
        float4 o = make_float4(acc[c][0], acc[c][1], acc[c][2], acc[c][3]);
        *(float4*)(out + (size_t)(b * CC + c) * HW + pix) = o;
    }
}

// ---- fallback: bounds-checked, reads data directly (if ws too small) -------
__global__ __launch_bounds__(256) void conv_kernel_safe(const float* __restrict__ kern,
                                                        const float* __restrict__ data,
                                                        float* __restrict__ out) {
    const int t     = blockIdx.x * 256 + threadIdx.x;
    const int per_b = HW / 4;
    const int b   = t / per_b;
    const int r   = t - b * per_b;
    const int pix = r * 4;
    const int y   = pix / WW;
    const int x   = pix - y * WW;

    const float* kb = kern + (size_t)b * (KK * KK) * HW + pix;

    float acc[CC][4];
    #pragma unroll
    for (int c = 0; c < CC; ++c)
        #pragma unroll
        for (int k = 0; k < 4; ++k) acc[c][k] = 0.f;

    #pragma unroll 1
    for (int u = 0; u < KK; ++u) {
        float4 kv[KK];
        #pragma unroll
        for (int v = 0; v < KK; ++v)
            kv[v] = *(const float4*)(kb + (size_t)(u * KK + v) * HW);

        const int drow  = y + PP - u;
        const bool rowok = (drow >= 0) && (drow < HH);

        #pragma unroll
        for (int c = 0; c < CC; ++c) {
            const float* dr = data + (size_t)(b * CC + c) * HW + drow * WW;
            float win[20];
            #pragma unroll
            for (int i = 0; i < 20; ++i) {
                int col = x + i - PP;
                win[i] = (rowok && col >= 0 && col < WW) ? dr[col] : 0.f;
            }
            #pragma unroll
            for (int v = 0; v < KK; ++v) {
                const int s = (KK - 1) - v;
                const float* kvp = (const float*)&kv[v];
                #pragma unroll
                for (int k = 0; k < 4; ++k)
                    acc[c][k] = fmaf(kvp[k], win[s + k], acc[c][k]);
            }
        }
    }

    #pragma unroll
    for (int c = 0; c < CC; ++c) {
        float4 o = make_float4(acc[c][0], acc[c][1], acc[c][2], acc[c][3]);
        *(float4*)(out + (size_t)(b * CC + c) * HW + pix) = o;
    }
}

extern "C" void kernel_launch(void* const* d_in, const int* in_sizes, int n_in,
                              void* d_out, int out_size, void* d_ws, size_t ws_size,
                              hipStream_t stream) {
    const float* data = (const float*)d_in[0];   // [B, C, H, W]
    const float* kern = (const float*)d_in[1];   // [B, K, K, H, W]
    float* out = (float*)d_out;                  // [B, C, H, W]

    const size_t padBytes = (size_t)BB * CC * HP * WP * sizeof(float);

    if (ws_size >= padBytes) {
        float* pad = (float*)d_ws;
        const int totalPad = BB * CC * HP * WP;
        pad_kernel<<<(totalPad + 255) / 256, 256, 0, stream>>>(data, pad);
        const int nBlocks = BB * NTY * NTX;      // 576
        conv_tiled<<<nBlocks, 256, 0, stream>>>(kern, pad, out);
    } else {
        const int nThreads = BB * HW / 4;
        conv_kernel_safe<<<nThreads / 256, 256, 0, stream>>>(kern, data, out);
    }
}

// Round 3
// 92.907 us; speedup vs baseline: 1.9614x; 1.2053x over previous
//
#include <hip/hip_runtime.h>

typedef float f32x4 __attribute__((ext_vector_type(4)));

#define BB 4
#define CC 3
#define HH 384
#define WW 384
#define KK 15
#define PP 7
#define HW (HH*WW)       // 147456

#define TX 128           // tile width (pixels)
#define TY 6             // tile height (pixels)
#define NTX (WW / TX)    // 3
#define NTY (HH / TY)    // 64
#define SROWS (TY + 2*PP)   // 20 staged rows
#define SCOLS 144           // staged cols: data col (x0-8) .. (x0+135), 16B-aligned
#define SV (SCOLS / 4)      // 36 float4 per row
#define NTHREADS 192        // 32 x-quads * 6 rows

// Single fused kernel:
//  - stage the data window [y0-7 .. y0+12] x [x0-8 .. x0+135] into LDS
//    (vectorized float4, each float4 uniformly in- or out-of-range -> zero)
//  - stream kernel taps (read-once, 531 MB) with nontemporal float4 loads
//  - out[y][x] = sum_{u,v} kern[b,u,v,y,x] * data[y+7-u, x+7-v]
__global__ __launch_bounds__(NTHREADS) void conv_fused(const float* __restrict__ kern,
                                                       const float* __restrict__ data,
                                                       float* __restrict__ out) {
    const int tid = threadIdx.x;
    const int blk = blockIdx.x;                 // 0 .. BB*NTY*NTX-1 (768)
    const int b   = blk / (NTY * NTX);
    const int r2  = blk - b * (NTY * NTX);
    const int ty  = r2 / NTX;
    const int tx  = r2 - ty * NTX;
    const int x0  = tx * TX;
    const int y0  = ty * TY;

    __shared__ __align__(16) float smem[CC][SROWS][SCOLS];   // 34,560 B

    // ---- stage data window into LDS ----
    // smem[c][r][i] = data[b, c, y0+r-7, x0-8+i]  (zero where out of range)
    const int NV = CC * SROWS * SV;   // 2160 float4s
    for (int i = tid; i < NV; i += NTHREADS) {
        int cx = i % SV;
        int r  = (i / SV) % SROWS;
        int c  = i / (SV * SROWS);
        int drow = y0 + r - PP;
        int dcol = x0 - 8 + cx * 4;
        f32x4 v = {0.f, 0.f, 0.f, 0.f};
        if (drow >= 0 && drow < HH && dcol >= 0 && dcol <= WW - 4)
            v = *(const f32x4*)(data + ((size_t)(b * CC + c) * HH + drow) * WW + dcol);
        *(f32x4*)&smem[c][r][cx * 4] = v;
    }
    __syncthreads();

    const int lx = tid & 31;       // x-quad within tile (0..31)
    const int ly = tid >> 5;       // row within tile (0..5)
    const int x  = x0 + lx * 4;
    const int y  = y0 + ly;
    const int pix = y * WW + x;

    const float* kb = kern + (size_t)b * (KK * KK) * HW + pix;

    float acc[CC][4];
    #pragma unroll
    for (int c = 0; c < CC; ++c)
        #pragma unroll
        for (int k = 0; k < 4; ++k) acc[c][k] = 0.f;

    #pragma unroll 1
    for (int u = 0; u < KK; ++u) {
        // 15 kernel taps for this u-row: the only large HBM stream (read-once -> nt)
        f32x4 kv[KK];
        #pragma unroll
        for (int v = 0; v < KK; ++v)
            kv[v] = __builtin_nontemporal_load(
                        (const f32x4*)(kb + (size_t)(u * KK + v) * HW));

        const int rr = ly + 2 * PP - u;    // staged row: ly + 14 - u, in [0,19]

        #pragma unroll
        for (int c = 0; c < CC; ++c) {
            // win[i] = data col (x0 - 8 + lx*4 + i); need i = (15-v)+k in [1,18]
            float win[20];
            #pragma unroll
            for (int w = 0; w < 5; ++w) {
                f32x4 d = *(const f32x4*)&smem[c][rr][lx * 4 + w * 4];
                win[w * 4 + 0] = d.x;
                win[w * 4 + 1] = d.y;
                win[w * 4 + 2] = d.z;
                win[w * 4 + 3] = d.w;
            }
            #pragma unroll
            for (int v = 0; v < KK; ++v) {
                const int s = KK - v;              // 15 - v
                const float* kvp = (const float*)&kv[v];
                #pragma unroll
                for (int k = 0; k < 4; ++k)
                    acc[c][k] = fmaf(kvp[k], win[s + k], acc[c][k]);
            }
        }
    }

    #pragma unroll
    for (int c = 0; c < CC; ++c) {
        f32x4 o = {acc[c][0], acc[c][1], acc[c][2], acc[c][3]};
        __builtin_nontemporal_store(o, (f32x4*)(out + (size_t)(b * CC + c) * HW + pix));
    }
}

extern "C" void kernel_launch(void* const* d_in, const int* in_sizes, int n_in,
                              void* d_out, int out_size, void* d_ws, size_t ws_size,
                              hipStream_t stream) {
    const float* data = (const float*)d_in[0];   // [B, C, H, W]
    const float* kern = (const float*)d_in[1];   // [B, K, K, H, W]
    float* out = (float*)d_out;                  // [B, C, H, W]

    const int nBlocks = BB * NTY * NTX;          // 768 = exactly 3 blocks/CU
    conv_fused<<<nBlocks, NTHREADS, 0, stream>>>(kern, data, out);
}